// Round 7
// baseline (150.543 us; speedup 1.0000x reference)
//
#include <hip/hip_runtime.h>

namespace {
constexpr int Bn = 8, Cn = 256, Hn = 96, Wn = 128;
constexpr int HWn = Hn * Wn;            // 12288
constexpr int CHWn = Cn * HWn;
constexpr int ND = 9;                   // 2*MD+1
constexpr int TILESH = Hn / 2;          // 48 h-pair tiles
constexpr int NBLK = Bn * TILESH;       // 384 blocks x 9 waves = 3456 waves
constexpr int PERX = NBLK / 8;          // 48 blocks/XCD -> one batch image per XCD
constexpr int CHALF = Cn / 2;           // 128 channel-steps per lane-half
}

// DPP lane shifts within 16-lane rows; bound_ctrl=true -> shifted-in lanes read 0
// (this IS the w-direction zero padding at tile edges).
__device__ __forceinline__ float dpp_shr1(float x) {  // lane i <- lane i-1 (row-local)
  return __int_as_float(__builtin_amdgcn_update_dpp(
      0, __float_as_int(x), 0x111 /*row_shr:1*/, 0xF, 0xF, true));
}
__device__ __forceinline__ float dpp_shl1(float x) {  // lane i <- lane i+1 (row-local)
  return __int_as_float(__builtin_amdgcn_update_dpp(
      0, __float_as_int(x), 0x101 /*row_shl:1*/, 0xF, 0xF, true));
}

struct Ch {
  float4 sa, sb, fa, fb;
};

// Block = 9 waves, one per dy, all covering the SAME (b, h-pair, full W):
// first rows are read 9x and second rows 3x through the shared L1 -> L2
// traffic drops ~3x vs one-dy-per-block. No barriers; waves free-run in
// near-lockstep (identical instruction stream).
__global__ __launch_bounds__(576) void corr_kernel(
    const float* __restrict__ first, const float* __restrict__ second,
    float* __restrict__ out)
{
  const int tid = threadIdx.x;
  const int dy = tid >> 6;           // wave index = dy (0..8)
  const int lane = tid & 63;
  const int bid = blockIdx.x;
  // XCD-aware swizzle: XCD x handles batch image b=x -> second re-reads stay in its L2.
  const int logical = (bid & 7) * PERX + (bid >> 3);
  const int b = logical / TILESH;
  const int h0 = (logical % TILESH) * 2;

  // lane layout: 4 groups of 16 lanes. group g = lane>>4:
  //   g0: row h0,   channels 0..127     g1: row h0+1, channels 0..127
  //   g2: row h0,   channels 128..255   g3: row h0+1, channels 128..255
  const int hs = (lane >> 4) & 1;    // row within pair (16-lane DPP group = one image row)
  const int chalf = lane >> 5;       // channel half
  const int w0 = (lane & 15) << 3;   // 8 pixels per lane

  const int gr = h0 + hs + dy - 4;                    // second source row
  const float m = (gr >= 0 && gr < Hn) ? 1.0f : 0.0f; // row OOB mask (uniform per 16-group)
  const int cg = min(max(gr, 0), Hn - 1);             // clamped (safe) row

  const float* ssrc = second + b * CHWn + chalf * CHALF * HWn + cg * Wn + w0;
  const float* fsrc = first + b * CHWn + chalf * CHALF * HWn + (h0 + hs) * Wn + w0;

  float acc[ND][8];
#pragma unroll
  for (int dx = 0; dx < ND; ++dx)
#pragma unroll
    for (int p = 0; p < 8; ++p) acc[dx][p] = 0.f;

  auto LOADCH = [&](int coff) -> Ch {
    Ch r;
    r.sa = *(const float4*)(ssrc + coff);
    r.sb = *(const float4*)(ssrc + coff + 4);
    r.fa = *(const float4*)(fsrc + coff);
    r.fb = *(const float4*)(fsrc + coff + 4);
    return r;
  };

  // Row-OOB mask hoisted to epilogue (acc scales linearly by m; DPP is row-local).
  auto COMP = [&](const Ch& ch) {
    const float s[16] = {
        dpp_shr1(ch.sb.x), dpp_shr1(ch.sb.y), dpp_shr1(ch.sb.z), dpp_shr1(ch.sb.w),
        ch.sa.x, ch.sa.y, ch.sa.z, ch.sa.w,
        ch.sb.x, ch.sb.y, ch.sb.z, ch.sb.w,
        dpp_shl1(ch.sa.x), dpp_shl1(ch.sa.y), dpp_shl1(ch.sa.z), dpp_shl1(ch.sa.w)};
    const float f[8] = {ch.fa.x, ch.fa.y, ch.fa.z, ch.fa.w,
                        ch.fb.x, ch.fb.y, ch.fb.z, ch.fb.w};
#pragma unroll
    for (int dx = 0; dx < ND; ++dx)
#pragma unroll
      for (int p = 0; p < 8; ++p)
        acc[dx][p] = fmaf(f[p], s[p + dx], acc[dx][p]);
  };

  // depth-2 register pipeline over this half's 128 channel-steps (R2's proven form)
  Ch L0 = LOADCH(0);
  Ch L1 = LOADCH(HWn);
  int coff = 2 * HWn;
#pragma unroll 1
  for (int it = 0; it < (CHALF - 2) / 2; ++it) {  // 63 iters
    Ch N0 = LOADCH(coff);
    Ch N1 = LOADCH(coff + HWn);
    COMP(L0);
    COMP(L1);
    L0 = N0;
    L1 = N1;
    coff += 2 * HWn;
  }
  COMP(L0);
  COMP(L1);

  // ---- register-only cross-half combine: lane l (+) lane l^32 (same pixel,
  // other channel half). After this every lane holds the full-C sum.
#pragma unroll
  for (int dx = 0; dx < ND; ++dx)
#pragma unroll
    for (int p = 0; p < 8; ++p)
      acc[dx][p] += __shfl_xor(acc[dx][p], 32);

  const float scale = m * (1.0f / Cn);
  float* obase = out + ((b * 81 + dy * ND) * Hn + (h0 + hs)) * Wn + w0;

  // split stores: lanes 0-31 write dx 0..4, lanes 32-63 write dx 5..8
  if (lane < 32) {
#pragma unroll
    for (int dx = 0; dx < 5; ++dx) {
      float4 o0 = make_float4(acc[dx][0] * scale, acc[dx][1] * scale,
                              acc[dx][2] * scale, acc[dx][3] * scale);
      float4 o1 = make_float4(acc[dx][4] * scale, acc[dx][5] * scale,
                              acc[dx][6] * scale, acc[dx][7] * scale);
      *(float4*)(obase + dx * HWn) = o0;
      *(float4*)(obase + dx * HWn + 4) = o1;
    }
  } else {
#pragma unroll
    for (int dx = 5; dx < ND; ++dx) {
      float4 o0 = make_float4(acc[dx][0] * scale, acc[dx][1] * scale,
                              acc[dx][2] * scale, acc[dx][3] * scale);
      float4 o1 = make_float4(acc[dx][4] * scale, acc[dx][5] * scale,
                              acc[dx][6] * scale, acc[dx][7] * scale);
      *(float4*)(obase + dx * HWn) = o0;
      *(float4*)(obase + dx * HWn + 4) = o1;
    }
  }
}

extern "C" void kernel_launch(void* const* d_in, const int* in_sizes, int n_in,
                              void* d_out, int out_size, void* d_ws, size_t ws_size,
                              hipStream_t stream) {
  const float* first = (const float*)d_in[0];
  const float* second = (const float*)d_in[1];
  float* out = (float*)d_out;
  corr_kernel<<<dim3(NBLK), dim3(576), 0, stream>>>(first, second, out);
}

// Round 8
// 138.572 us; speedup vs baseline: 1.0864x; 1.0864x over previous
//
#include <hip/hip_runtime.h>

typedef _Float16 half2v __attribute__((ext_vector_type(2)));

namespace {
constexpr int Bn = 8, Cn = 256, Hn = 96, Wn = 128;
constexpr int HWn = Hn * Wn;          // 12288
constexpr int CHWn = Cn * HWn;
constexpr int CPn = Cn / 2;           // 128 channel-pairs
constexpr int ND = 9;
constexpr int TH = 4;                 // h-rows per block
constexpr int HQ = Hn / TH;           // 24
constexpr int NBLK = Bn * HQ;         // 192 blocks, 9 waves each
constexpr size_t WSF_U32 = (size_t)Bn * CPn * HWn;   // u32 per packed array
constexpr size_t WS_NEED = 2 * WSF_U32 * 4;          // ~100.7 MB
constexpr int ROWP = 132;             // LDS row pitch (u32): 16B-aligned, rows offset 4 banks
constexpr int STEPSZ = 16 * ROWP;     // u32 per pair-step (12 s-rows + 4 f-rows)
}

__device__ __forceinline__ unsigned dpp_shr1(unsigned x) {  // lane i <- i-1 (16-row local)
  return (unsigned)__builtin_amdgcn_update_dpp(0, (int)x, 0x111, 0xF, 0xF, true);
}
__device__ __forceinline__ unsigned dpp_shl1(unsigned x) {  // lane i <- i+1
  return (unsigned)__builtin_amdgcn_update_dpp(0, (int)x, 0x101, 0xF, 0xF, true);
}

__device__ __forceinline__ float dot2h(unsigned a, unsigned b, float c) {
#if __has_builtin(__builtin_amdgcn_fdot2)
  return __builtin_amdgcn_fdot2(__builtin_bit_cast(half2v, a),
                                __builtin_bit_cast(half2v, b), c, false);
#else
  float d;
  asm("v_dot2_f32_f16 %0, %1, %2, %3" : "=v"(d) : "v"(a), "v"(b), "v"(c));
  return d;
#endif
}

// ---------- prepass: fp32 -> fp16 channel-pair packed ----------
__global__ __launch_bounds__(256) void prepack(
    const float* __restrict__ fin, const float* __restrict__ sin_,
    unsigned* __restrict__ wf, unsigned* __restrict__ wsp)
{
  const int total = Bn * CPn * Hn * (Wn / 4);   // 16B quads
  for (int q = blockIdx.x * blockDim.x + threadIdx.x; q < total;
       q += gridDim.x * blockDim.x) {
    const int w4 = q & 31;
    const int h = (q >> 5) % Hn;
    const int bcp = q / (32 * Hn);
    const int b = bcp >> 7, cp = bcp & 127;
    const int i0 = ((b * Cn + 2 * cp) * Hn + h) * Wn + w4 * 4;
    float4 fa = *(const float4*)(fin + i0);
    float4 fb = *(const float4*)(fin + i0 + HWn);
    float4 sa = *(const float4*)(sin_ + i0);
    float4 sb = *(const float4*)(sin_ + i0 + HWn);
    uint4 pf, ps;
    pf.x = __builtin_bit_cast(unsigned, __builtin_amdgcn_cvt_pkrtz(fa.x, fb.x));
    pf.y = __builtin_bit_cast(unsigned, __builtin_amdgcn_cvt_pkrtz(fa.y, fb.y));
    pf.z = __builtin_bit_cast(unsigned, __builtin_amdgcn_cvt_pkrtz(fa.z, fb.z));
    pf.w = __builtin_bit_cast(unsigned, __builtin_amdgcn_cvt_pkrtz(fa.w, fb.w));
    ps.x = __builtin_bit_cast(unsigned, __builtin_amdgcn_cvt_pkrtz(sa.x, sb.x));
    ps.y = __builtin_bit_cast(unsigned, __builtin_amdgcn_cvt_pkrtz(sa.y, sb.y));
    ps.z = __builtin_bit_cast(unsigned, __builtin_amdgcn_cvt_pkrtz(sa.z, sb.z));
    ps.w = __builtin_bit_cast(unsigned, __builtin_amdgcn_cvt_pkrtz(sa.w, sb.w));
    *(uint4*)(wf + (size_t)q * 4) = pf;
    *(uint4*)(wsp + (size_t)q * 4) = ps;
  }
}

// ---------- main: LDS-staged fp16 dot2 correlation ----------
__global__ __launch_bounds__(576) void corr_dot2(
    const unsigned* __restrict__ wf, const unsigned* __restrict__ wsp,
    float* __restrict__ out)
{
  __shared__ __align__(16) unsigned LB[2][2 * STEPSZ];  // 33,792 B

  const int tid = threadIdx.x;
  const int dy = tid >> 6;          // wave = dy
  const int lane = tid & 63;
  const int hs = (lane >> 4) & 3;   // h-row within tile (16-lane group = full image row)
  const int w0 = (lane & 15) << 3;  // 8 pixels per lane

  const int bid = blockIdx.x;
  const int logical = (bid & 7) * (NBLK / 8) + (bid >> 3);  // XCD: image b per XCD
  const int b = logical / HQ;
  const int h0 = (logical % HQ) * TH;

  // staging tasks: per pair-step 16 rows (12 s + 4 f) x 32 lanes (16B each) = 512;
  // chunk = 2 steps = 1024 tasks over 576 lanes -> up to 2 tasks/lane.
  const int t0 = tid, t1 = tid + 576;

  float acc[ND][8];
#pragma unroll
  for (int dx = 0; dx < ND; ++dx)
#pragma unroll
    for (int p = 0; p < 8; ++p) acc[dx][p] = 0.f;

  uint4 stg0, stg1;
  auto LOADT = [&](int t, int k, uint4& v) {
    const int step = t >> 9;          // 0/1 within chunk
    const int r = (t >> 5) & 15;      // row task
    const int li = t & 31;            // 16B column
    const int cp = 2 * k + step;
    if (r < 12) {
      const int grow = h0 - 4 + r;
      if (grow >= 0 && grow < Hn)
        v = *(const uint4*)(wsp + ((size_t)(b * CPn + cp) * Hn + grow) * Wn + li * 4);
      else
        v = make_uint4(0, 0, 0, 0);
    } else {
      const int hr = h0 + (r - 12);
      v = *(const uint4*)(wf + ((size_t)(b * CPn + cp) * Hn + hr) * Wn + li * 4);
    }
  };
  auto LOADS = [&](int k) {
    LOADT(t0, k, stg0);
    if (t1 < 1024) LOADT(t1, k, stg1);
  };
  auto WRITET = [&](int t, unsigned* lb, const uint4& v) {
    const int step = t >> 9;
    const int r = (t >> 5) & 15;
    const int li = t & 31;
    *(uint4*)(lb + step * STEPSZ + r * ROWP + li * 4) = v;
  };
  auto WRITES = [&](unsigned* lb) {
    WRITET(t0, lb, stg0);
    if (t1 < 1024) WRITET(t1, lb, stg1);
  };

  auto COMPUTE = [&](const unsigned* lb) {
#pragma unroll
    for (int step = 0; step < 2; ++step) {
      const unsigned* base = lb + step * STEPSZ;
      const unsigned* srow = base + (hs + dy) * ROWP + w0;
      const unsigned* frow = base + (12 + hs) * ROWP + w0;
      uint4 sA = *(const uint4*)(srow);
      uint4 sB = *(const uint4*)(srow + 4);
      uint4 fA = *(const uint4*)(frow);
      uint4 fB = *(const uint4*)(frow + 4);
      const unsigned o0 = sA.x, o1 = sA.y, o2 = sA.z, o3 = sA.w;
      const unsigned o4 = sB.x, o5 = sB.y, o6 = sB.z, o7 = sB.w;
      // halos from neighbor lanes (16-lane group = full row; edges zero = image pad)
      const unsigned sw[16] = {
          dpp_shr1(o4), dpp_shr1(o5), dpp_shr1(o6), dpp_shr1(o7),
          o0, o1, o2, o3, o4, o5, o6, o7,
          dpp_shl1(o0), dpp_shl1(o1), dpp_shl1(o2), dpp_shl1(o3)};
      const unsigned fv[8] = {fA.x, fA.y, fA.z, fA.w, fB.x, fB.y, fB.z, fB.w};
#pragma unroll
      for (int dx = 0; dx < ND; ++dx)
#pragma unroll
        for (int p = 0; p < 8; ++p)
          acc[dx][p] = dot2h(fv[p], sw[p + dx], acc[dx][p]);
    }
  };

  // pipeline: chunk = 2 channel-pairs, double-buffered, 1 barrier/chunk
  LOADS(0);
  WRITES(&LB[0][0]);
  __syncthreads();
#pragma unroll 1
  for (int k = 0; k < CPn / 2; ++k) {   // 64 chunks
    if (k < CPn / 2 - 1) LOADS(k + 1);
    COMPUTE(&LB[k & 1][0]);
    if (k < CPn / 2 - 1) WRITES(&LB[(k + 1) & 1][0]);
    __syncthreads();
  }

  const float sc = 1.0f / Cn;
  float* obase = out + ((size_t)(b * 81 + dy * ND) * Hn + (h0 + hs)) * Wn + w0;
#pragma unroll
  for (int dx = 0; dx < ND; ++dx) {
    float4 q0 = make_float4(acc[dx][0] * sc, acc[dx][1] * sc,
                            acc[dx][2] * sc, acc[dx][3] * sc);
    float4 q1 = make_float4(acc[dx][4] * sc, acc[dx][5] * sc,
                            acc[dx][6] * sc, acc[dx][7] * sc);
    *(float4*)(obase + (size_t)dx * HWn) = q0;
    *(float4*)(obase + (size_t)dx * HWn + 4) = q1;
  }
}

// ---------- fallback (proven R2 kernel) if ws is too small ----------
__device__ __forceinline__ float fdpp_shr1(float x) {
  return __int_as_float(__builtin_amdgcn_update_dpp(0, __float_as_int(x), 0x111, 0xF, 0xF, true));
}
__device__ __forceinline__ float fdpp_shl1(float x) {
  return __int_as_float(__builtin_amdgcn_update_dpp(0, __float_as_int(x), 0x101, 0xF, 0xF, true));
}
struct Ch { float4 sa, sb, fa, fb; };

__global__ __launch_bounds__(64) void corr_r2(
    const float* __restrict__ first, const float* __restrict__ second,
    float* __restrict__ out)
{
  const int lane = threadIdx.x;
  const int bid = blockIdx.x;
  const int logical = (bid & 7) * 216 + (bid >> 3);
  const int dy = logical % ND;
  const int t = logical / ND;
  const int b = t / 24;
  const int h0 = (t % 24) * 4;
  const int hs = lane >> 4;
  const int w0 = (lane & 15) << 3;
  const int gr = h0 + hs + dy - 4;
  const float m = (gr >= 0 && gr < Hn) ? 1.0f : 0.0f;
  const int cg = min(max(gr, 0), Hn - 1);
  const float* ssrc = second + b * CHWn + cg * Wn + w0;
  const float* fsrc = first + b * CHWn + (h0 + hs) * Wn + w0;
  float acc[ND][8];
#pragma unroll
  for (int dx = 0; dx < ND; ++dx)
#pragma unroll
    for (int p = 0; p < 8; ++p) acc[dx][p] = 0.f;
  auto LOADCH = [&](int coff) -> Ch {
    Ch r;
    r.sa = *(const float4*)(ssrc + coff);
    r.sb = *(const float4*)(ssrc + coff + 4);
    r.fa = *(const float4*)(fsrc + coff);
    r.fb = *(const float4*)(fsrc + coff + 4);
    return r;
  };
  auto COMP = [&](const Ch& ch) {
    const float sa0 = ch.sa.x * m, sa1 = ch.sa.y * m, sa2 = ch.sa.z * m, sa3 = ch.sa.w * m;
    const float sb0 = ch.sb.x * m, sb1 = ch.sb.y * m, sb2 = ch.sb.z * m, sb3 = ch.sb.w * m;
    const float s[16] = {fdpp_shr1(sb0), fdpp_shr1(sb1), fdpp_shr1(sb2), fdpp_shr1(sb3),
                         sa0, sa1, sa2, sa3, sb0, sb1, sb2, sb3,
                         fdpp_shl1(sa0), fdpp_shl1(sa1), fdpp_shl1(sa2), fdpp_shl1(sa3)};
    const float f[8] = {ch.fa.x, ch.fa.y, ch.fa.z, ch.fa.w,
                        ch.fb.x, ch.fb.y, ch.fb.z, ch.fb.w};
#pragma unroll
    for (int dx = 0; dx < ND; ++dx)
#pragma unroll
      for (int p = 0; p < 8; ++p) acc[dx][p] = fmaf(f[p], s[p + dx], acc[dx][p]);
  };
  Ch L0 = LOADCH(0);
  Ch L1 = LOADCH(HWn);
  int coff = 2 * HWn;
#pragma unroll 1
  for (int it = 0; it < (Cn - 2) / 2; ++it) {
    Ch N0 = LOADCH(coff);
    Ch N1 = LOADCH(coff + HWn);
    COMP(L0); COMP(L1);
    L0 = N0; L1 = N1;
    coff += 2 * HWn;
  }
  COMP(L0); COMP(L1);
  const float sc = 1.0f / Cn;
  float* obase = out + ((b * 81 + dy * ND) * Hn + (h0 + hs)) * Wn + w0;
#pragma unroll
  for (int dx = 0; dx < ND; ++dx) {
    float4 o0 = make_float4(acc[dx][0] * sc, acc[dx][1] * sc, acc[dx][2] * sc, acc[dx][3] * sc);
    float4 o1 = make_float4(acc[dx][4] * sc, acc[dx][5] * sc, acc[dx][6] * sc, acc[dx][7] * sc);
    *(float4*)(obase + dx * HWn) = o0;
    *(float4*)(obase + dx * HWn + 4) = o1;
  }
}

extern "C" void kernel_launch(void* const* d_in, const int* in_sizes, int n_in,
                              void* d_out, int out_size, void* d_ws, size_t ws_size,
                              hipStream_t stream) {
  const float* first = (const float*)d_in[0];
  const float* second = (const float*)d_in[1];
  float* out = (float*)d_out;
  if (ws_size >= WS_NEED) {
    unsigned* wf = (unsigned*)d_ws;
    unsigned* wsp = wf + WSF_U32;
    prepack<<<dim3(2048), dim3(256), 0, stream>>>(first, second, wf, wsp);
    corr_dot2<<<dim3(NBLK), dim3(576), 0, stream>>>(wf, wsp, out);
  } else {
    corr_r2<<<dim3(1728), dim3(64), 0, stream>>>(first, second, out);
  }
}